// Round 1
// baseline (360.767 us; speedup 1.0000x reference)
//
#include <hip/hip_runtime.h>
#include <hip/hip_bf16.h>
#include <stdint.h>

#define B_ 16
#define N_ 4096
#define E_ 65536
#define C_ 128   // CIN == COUT

using f32x4 = __attribute__((ext_vector_type(4))) float;
using s16x8 = __attribute__((ext_vector_type(8))) short;

__device__ __forceinline__ unsigned short f2bf(float f) {
  unsigned int u = __builtin_bit_cast(unsigned int, f);
  u = (u + 0x7FFFu + ((u >> 16) & 1u)) >> 16;
  return (unsigned short)u;
}

// ---- CSR build ----------------------------------------------------------

__global__ __launch_bounds__(256) void zero_kernel(int* __restrict__ p) {
  p[blockIdx.x * 256 + threadIdx.x] = 0;
}

__global__ __launch_bounds__(256) void hist_kernel(const int* __restrict__ rows,
                                                   int* __restrict__ cnt) {
  int eg = blockIdx.x * 256 + threadIdx.x;   // 0 .. B*E-1
  int b = eg >> 16;                          // E = 65536
  int r = rows[eg];
  atomicAdd(&cnt[b * N_ + r], 1);
}

__global__ __launch_bounds__(256) void scan_kernel(const int* __restrict__ cnt,
                                                   int* __restrict__ off) {
  __shared__ int psum[256];
  int b = blockIdx.x, t = threadIdx.x;
  int local[16];
  int s = 0;
  int base = b * N_ + t * 16;
  #pragma unroll
  for (int i = 0; i < 16; ++i) { local[i] = cnt[base + i]; s += local[i]; }
  psum[t] = s;
  __syncthreads();
  if (t == 0) {
    int run = 0;
    for (int i = 0; i < 256; ++i) { int v = psum[i]; psum[i] = run; run += v; }
  }
  __syncthreads();
  int run = psum[t];
  int ob = b * (N_ + 1) + t * 16;
  #pragma unroll
  for (int i = 0; i < 16; ++i) { off[ob + i] = run; run += local[i]; }
  if (t == 255) off[b * (N_ + 1) + N_] = run;
}

__global__ __launch_bounds__(256) void scatter_kernel(const int* __restrict__ rows,
                                                      const int* __restrict__ off,
                                                      int* __restrict__ cur,
                                                      int* __restrict__ perm) {
  int eg = blockIdx.x * 256 + threadIdx.x;
  int b = eg >> 16;
  int e = eg & (E_ - 1);
  int r = rows[eg];
  int slot = off[b * (N_ + 1) + r] + atomicAdd(&cur[b * N_ + r], 1);
  perm[b * E_ + slot] = e;
}

// ---- SpMM: dst[row] = ca * sum_{e in row} vals[e]*src[cols[e]] + cb * sub[row]

__global__ __launch_bounds__(256) void spmm_kernel(const float* __restrict__ src,
                                                   const float* sub,
                                                   float* dst,
                                                   const int* __restrict__ perm,
                                                   const int* __restrict__ off,
                                                   const int* __restrict__ cols,
                                                   const float* __restrict__ vals,
                                                   float ca, float cb) {
  int lane = threadIdx.x & 63;
  int rg = blockIdx.x * 4 + (threadIdx.x >> 6);   // global row, 0..B*N-1
  int b = rg >> 12;                               // N = 4096
  int n = rg & (N_ - 1);
  int start = off[b * (N_ + 1) + n];
  int end   = off[b * (N_ + 1) + n + 1];
  const int*   permb = perm + b * E_;
  const int*   colsb = cols + b * E_;
  const float* valsb = vals + b * E_;
  const float* srcb  = src + (size_t)b * N_ * C_;
  float ax = 0.f, ay = 0.f;
  for (int s0 = start; s0 < end; s0 += 64) {
    int m = end - s0; if (m > 64) m = 64;
    int c = 0; float v = 0.f;
    if (lane < m) {
      int e = permb[s0 + lane];
      c = colsb[e];
      v = valsb[e];
    }
    for (int i = 0; i < m; ++i) {
      int   ci = __shfl(c, i);
      float vi = __shfl(v, i);
      const float2 xv = *reinterpret_cast<const float2*>(srcb + (size_t)ci * C_ + lane * 2);
      ax = fmaf(vi, xv.x, ax);
      ay = fmaf(vi, xv.y, ay);
    }
  }
  size_t ro = (size_t)rg * C_ + lane * 2;
  float ox = ca * ax, oy = ca * ay;
  if (sub) {
    const float2 sv = *reinterpret_cast<const float2*>(sub + ro);
    ox = fmaf(cb, sv.x, ox);
    oy = fmaf(cb, sv.y, oy);
  }
  *reinterpret_cast<float2*>(dst + ro) = make_float2(ox, oy);
}

// ---- W fragment packing: bf16, per-lane MFMA B-operand order -------------
// slot index = ((ks*8 + ct)*64 + lane)*8 + j  maps to  W[k/128][k%128][ct*16 + lane%16]
// with k = ks*32 + (lane/16)*8 + j   (consistent bijection with the A-side pack)

__global__ __launch_bounds__(256) void wfrag_kernel(const float* __restrict__ w,
                                                    unsigned short* __restrict__ wf) {
  int tid = blockIdx.x * 256 + threadIdx.x;   // 0..65535
  int j  = tid & 7;
  int l  = (tid >> 3) & 63;
  int ct = (tid >> 9) & 7;
  int ks = tid >> 12;
  int g  = l >> 4;
  int k  = ks * 32 + g * 8 + j;
  int kk = k >> 7;
  int i  = k & 127;
  int o  = ct * 16 + (l & 15);
  wf[tid] = f2bf(w[(kk * C_ + i) * C_ + o]);
}

// ---- fused GEMM: out = relu(bias + x@W0 + c1@W1 + c2@W2 + c3@W3) ---------
// block = 256 (4 waves); each wave: 16 rows x 128 cols, K = 512 in 16 steps.
// NOTE: c3 may alias out (wave reads exactly the rows it later writes).

__global__ __launch_bounds__(256) void gemm_kernel(const float* __restrict__ x,
                                                   const float* __restrict__ c1,
                                                   const float* __restrict__ c2,
                                                   const float* c3,
                                                   const unsigned short* __restrict__ wf,
                                                   const float* __restrict__ bias,
                                                   float* out) {
  int lane = threadIdx.x & 63;
  int w = threadIdx.x >> 6;
  int mb = blockIdx.x * 64 + w * 16;
  int g  = lane >> 4;
  int rl = lane & 15;
  const float* srcs[4] = {x, c1, c2, c3};
  f32x4 acc[8];
  #pragma unroll
  for (int t = 0; t < 8; ++t) acc[t] = (f32x4){0.f, 0.f, 0.f, 0.f};
  size_t mrow = (size_t)(mb + rl) * C_;
  for (int ks = 0; ks < 16; ++ks) {
    const float* ap = srcs[ks >> 2] + mrow + (ks & 3) * 32 + g * 8;
    float4 a0 = *reinterpret_cast<const float4*>(ap);
    float4 a1 = *reinterpret_cast<const float4*>(ap + 4);
    s16x8 af;
    af[0] = (short)f2bf(a0.x); af[1] = (short)f2bf(a0.y);
    af[2] = (short)f2bf(a0.z); af[3] = (short)f2bf(a0.w);
    af[4] = (short)f2bf(a1.x); af[5] = (short)f2bf(a1.y);
    af[6] = (short)f2bf(a1.z); af[7] = (short)f2bf(a1.w);
    const s16x8* wp = reinterpret_cast<const s16x8*>(wf) + (ks * 8) * 64 + lane;
    #pragma unroll
    for (int ct = 0; ct < 8; ++ct) {
      s16x8 bfv = wp[ct * 64];
      acc[ct] = __builtin_amdgcn_mfma_f32_16x16x32_bf16(af, bfv, acc[ct], 0, 0, 0);
    }
  }
  #pragma unroll
  for (int ct = 0; ct < 8; ++ct) {
    int o = ct * 16 + rl;
    float bo = bias[o];
    #pragma unroll
    for (int r = 0; r < 4; ++r) {
      int m = mb + g * 4 + r;
      float val = acc[ct][r] + bo;
      out[(size_t)m * C_ + o] = val > 0.f ? val : 0.f;
    }
  }
}

// ---- launch --------------------------------------------------------------

extern "C" void kernel_launch(void* const* d_in, const int* in_sizes, int n_in,
                              void* d_out, int out_size, void* d_ws, size_t ws_size,
                              hipStream_t stream) {
  (void)in_sizes; (void)n_in; (void)out_size; (void)ws_size;
  const float* x    = (const float*)d_in[0];
  const float* vals = (const float*)d_in[1];
  const float* wts  = (const float*)d_in[2];
  const float* bias = (const float*)d_in[3];
  const int*   rows = (const int*)d_in[4];
  const int*   cols = (const int*)d_in[5];
  float* out = (float*)d_out;

  const size_t S = (size_t)B_ * N_ * C_ * sizeof(float);   // 33.5 MB
  char* ws = (char*)d_ws;
  float* cheb1 = (float*)ws;
  float* cheb2 = (float*)(ws + S);
  char* meta = ws + 2 * S;
  int* cnt  = (int*)meta;                        // B*N*4      = 262144 B
  int* cur  = (int*)(meta + 262144);             // B*N*4      = 262144 B
  int* off  = (int*)(meta + 524288);             // B*(N+1)*4  = 262208 B
  int* perm = (int*)(meta + 1048576);            // B*E*4      = 4 MB
  unsigned short* wf = (unsigned short*)(meta + 1048576 + 4194304);  // 128 KB

  // zero cnt + cur (131072 ints)
  zero_kernel<<<512, 256, 0, stream>>>(cnt);
  wfrag_kernel<<<256, 256, 0, stream>>>(wts, wf);
  hist_kernel<<<(B_ * E_) / 256, 256, 0, stream>>>(rows, cnt);
  scan_kernel<<<B_, 256, 0, stream>>>(cnt, off);
  scatter_kernel<<<(B_ * E_) / 256, 256, 0, stream>>>(rows, off, cur, perm);
  // cheb1 = L x
  spmm_kernel<<<(B_ * N_) / 4, 256, 0, stream>>>(x, nullptr, cheb1, perm, off, cols, vals, 1.f, 0.f);
  // cheb2 = 2 L cheb1 - x
  spmm_kernel<<<(B_ * N_) / 4, 256, 0, stream>>>(cheb1, x, cheb2, perm, off, cols, vals, 2.f, -1.f);
  // cheb3 = 2 L cheb2 - cheb1   (stored in d_out)
  spmm_kernel<<<(B_ * N_) / 4, 256, 0, stream>>>(cheb2, cheb1, out, perm, off, cols, vals, 2.f, -1.f);
  // out = relu(bias + x@W0 + c1@W1 + c2@W2 + c3@W3)
  gemm_kernel<<<(B_ * N_) / 64, 256, 0, stream>>>(x, cheb1, cheb2, out, wf, bias, out);
}

// Round 2
// 255.977 us; speedup vs baseline: 1.4094x; 1.4094x over previous
//
#include <hip/hip_runtime.h>
#include <hip/hip_bf16.h>
#include <stdint.h>

#define B_ 16
#define N_ 4096
#define E_ 65536
#define C_ 128   // CIN == COUT

using f32x4 = __attribute__((ext_vector_type(4))) float;
using s16x8 = __attribute__((ext_vector_type(8))) short;

__device__ __forceinline__ unsigned short f2bf(float f) {
  unsigned int u = __builtin_bit_cast(unsigned int, f);
  u = (u + 0x7FFFu + ((u >> 16) & 1u)) >> 16;
  return (unsigned short)u;
}

// ---- CSR build ----------------------------------------------------------

__global__ __launch_bounds__(256) void zero_kernel(int* __restrict__ p) {
  p[blockIdx.x * 256 + threadIdx.x] = 0;
}

__global__ __launch_bounds__(256) void hist_kernel(const int* __restrict__ rows,
                                                   int* __restrict__ cnt) {
  int eg = blockIdx.x * 256 + threadIdx.x;   // 0 .. B*E-1
  int b = eg >> 16;                          // E = 65536
  int r = rows[eg];
  atomicAdd(&cnt[b * N_ + r], 1);
}

__global__ __launch_bounds__(256) void scan_kernel(const int* __restrict__ cnt,
                                                   int* __restrict__ off) {
  __shared__ int psum[256];
  int b = blockIdx.x, t = threadIdx.x;
  int local[16];
  int s = 0;
  int base = b * N_ + t * 16;
  #pragma unroll
  for (int i = 0; i < 16; ++i) { local[i] = cnt[base + i]; s += local[i]; }
  psum[t] = s;
  __syncthreads();
  if (t == 0) {
    int run = 0;
    for (int i = 0; i < 256; ++i) { int v = psum[i]; psum[i] = run; run += v; }
  }
  __syncthreads();
  int run = psum[t];
  int ob = b * (N_ + 1) + t * 16;
  #pragma unroll
  for (int i = 0; i < 16; ++i) { off[ob + i] = run; run += local[i]; }
  if (t == 255) off[b * (N_ + 1) + N_] = run;
}

// scatter edges into row-sorted order carrying (col, val) payload
__global__ __launch_bounds__(256) void scatter_kernel(const int* __restrict__ rows,
                                                      const int* __restrict__ cols,
                                                      const float* __restrict__ vals,
                                                      const int* __restrict__ off,
                                                      int* __restrict__ cur,
                                                      int2* __restrict__ ecv) {
  int eg = blockIdx.x * 256 + threadIdx.x;
  int b = eg >> 16;
  int r = rows[eg];
  int slot = off[b * (N_ + 1) + r] + atomicAdd(&cur[b * N_ + r], 1);
  ecv[b * E_ + slot] = make_int2(cols[eg], __float_as_int(vals[eg]));
}

// ---- SpMM: dst[row] = ca * sum_{e in row} val_e * src[col_e] + cb * sub[row]
// wave = 4 edge-slots x 16 channel-lanes; XCD-pinned batches (xcd x -> b=2x,2x+1)

__global__ __launch_bounds__(256) void spmm_kernel(const float* __restrict__ src,
                                                   const float* sub,
                                                   float* dst,
                                                   const int2* __restrict__ ecv,
                                                   const int* __restrict__ off,
                                                   float ca, float cb) {
  int lane = threadIdx.x & 63;
  int wv   = threadIdx.x >> 6;
  int xcd  = blockIdx.x & 7;
  int j    = blockIdx.x >> 3;          // 0..2047
  int b    = xcd * 2 + (j >> 10);
  int n    = ((j & 1023) << 2) | wv;   // row within batch
  int eg   = lane >> 4;                // edge slot 0..3
  int cl   = lane & 15;                // channel group (8 floats)
  int start = off[b * (N_ + 1) + n];
  int end   = off[b * (N_ + 1) + n + 1];
  const int2*  ecvb = ecv + b * E_;
  const float* srcb = src + (size_t)b * N_ * C_;
  float acc[8];
  #pragma unroll
  for (int t = 0; t < 8; ++t) acc[t] = 0.f;
  for (int s = start + eg; s < end; s += 4) {
    int2 cv = ecvb[s];
    float v = __builtin_bit_cast(float, cv.y);
    const float4* xp = reinterpret_cast<const float4*>(srcb + (size_t)cv.x * C_ + cl * 8);
    float4 x0 = xp[0];
    float4 x1 = xp[1];
    acc[0] = fmaf(v, x0.x, acc[0]);
    acc[1] = fmaf(v, x0.y, acc[1]);
    acc[2] = fmaf(v, x0.z, acc[2]);
    acc[3] = fmaf(v, x0.w, acc[3]);
    acc[4] = fmaf(v, x1.x, acc[4]);
    acc[5] = fmaf(v, x1.y, acc[5]);
    acc[6] = fmaf(v, x1.z, acc[6]);
    acc[7] = fmaf(v, x1.w, acc[7]);
  }
  // reduce the 4 edge-slots
  #pragma unroll
  for (int t = 0; t < 8; ++t) {
    acc[t] += __shfl_xor(acc[t], 16);
    acc[t] += __shfl_xor(acc[t], 32);
  }
  if (eg == 0) {
    size_t ro = ((size_t)(b * N_ + n)) * C_ + cl * 8;
    float o[8];
    #pragma unroll
    for (int t = 0; t < 8; ++t) o[t] = ca * acc[t];
    if (sub) {
      const float4* sp = reinterpret_cast<const float4*>(sub + ro);
      float4 s0 = sp[0];
      float4 s1 = sp[1];
      o[0] = fmaf(cb, s0.x, o[0]);
      o[1] = fmaf(cb, s0.y, o[1]);
      o[2] = fmaf(cb, s0.z, o[2]);
      o[3] = fmaf(cb, s0.w, o[3]);
      o[4] = fmaf(cb, s1.x, o[4]);
      o[5] = fmaf(cb, s1.y, o[5]);
      o[6] = fmaf(cb, s1.z, o[6]);
      o[7] = fmaf(cb, s1.w, o[7]);
    }
    float4* dp = reinterpret_cast<float4*>(dst + ro);
    dp[0] = make_float4(o[0], o[1], o[2], o[3]);
    dp[1] = make_float4(o[4], o[5], o[6], o[7]);
  }
}

// ---- W fragment packing: bf16, per-lane MFMA B-operand order -------------

__global__ __launch_bounds__(256) void wfrag_kernel(const float* __restrict__ w,
                                                    unsigned short* __restrict__ wf) {
  int tid = blockIdx.x * 256 + threadIdx.x;   // 0..65535
  int j  = tid & 7;
  int l  = (tid >> 3) & 63;
  int ct = (tid >> 9) & 7;
  int ks = tid >> 12;
  int g  = l >> 4;
  int k  = ks * 32 + g * 8 + j;
  int kk = k >> 7;
  int i  = k & 127;
  int o  = ct * 16 + (l & 15);
  wf[tid] = f2bf(w[(kk * C_ + i) * C_ + o]);
}

// ---- fused GEMM: out = relu(bias + x@W0 + c1@W1 + c2@W2 + c3@W3) ---------
// block = 256 (4 waves); each wave: 16 rows x 128 cols, K = 512 in 16 steps.
// NOTE: c3 may alias out (wave reads exactly the rows it later writes).

__global__ __launch_bounds__(256) void gemm_kernel(const float* __restrict__ x,
                                                   const float* __restrict__ c1,
                                                   const float* __restrict__ c2,
                                                   const float* c3,
                                                   const unsigned short* __restrict__ wf,
                                                   const float* __restrict__ bias,
                                                   float* out) {
  int lane = threadIdx.x & 63;
  int w = threadIdx.x >> 6;
  int xcd = blockIdx.x & 7;
  int j = blockIdx.x >> 3;                 // 0..127
  int b = xcd * 2 + (j >> 6);
  int mb = b * N_ + ((j & 63) << 6) + w * 16;
  int g  = lane >> 4;
  int rl = lane & 15;
  const float* srcs[4] = {x, c1, c2, c3};
  f32x4 acc[8];
  #pragma unroll
  for (int t = 0; t < 8; ++t) acc[t] = (f32x4){0.f, 0.f, 0.f, 0.f};
  size_t mrow = (size_t)(mb + rl) * C_;
  for (int ks = 0; ks < 16; ++ks) {
    const float* ap = srcs[ks >> 2] + mrow + (ks & 3) * 32 + g * 8;
    float4 a0 = *reinterpret_cast<const float4*>(ap);
    float4 a1 = *reinterpret_cast<const float4*>(ap + 4);
    s16x8 af;
    af[0] = (short)f2bf(a0.x); af[1] = (short)f2bf(a0.y);
    af[2] = (short)f2bf(a0.z); af[3] = (short)f2bf(a0.w);
    af[4] = (short)f2bf(a1.x); af[5] = (short)f2bf(a1.y);
    af[6] = (short)f2bf(a1.z); af[7] = (short)f2bf(a1.w);
    const s16x8* wp = reinterpret_cast<const s16x8*>(wf) + (ks * 8) * 64 + lane;
    #pragma unroll
    for (int ct = 0; ct < 8; ++ct) {
      s16x8 bfv = wp[ct * 64];
      acc[ct] = __builtin_amdgcn_mfma_f32_16x16x32_bf16(af, bfv, acc[ct], 0, 0, 0);
    }
  }
  #pragma unroll
  for (int ct = 0; ct < 8; ++ct) {
    int o = ct * 16 + rl;
    float bo = bias[o];
    #pragma unroll
    for (int r = 0; r < 4; ++r) {
      int m = mb + g * 4 + r;
      float val = acc[ct][r] + bo;
      out[(size_t)m * C_ + o] = val > 0.f ? val : 0.f;
    }
  }
}

// ---- launch --------------------------------------------------------------

extern "C" void kernel_launch(void* const* d_in, const int* in_sizes, int n_in,
                              void* d_out, int out_size, void* d_ws, size_t ws_size,
                              hipStream_t stream) {
  (void)in_sizes; (void)n_in; (void)out_size; (void)ws_size;
  const float* x    = (const float*)d_in[0];
  const float* vals = (const float*)d_in[1];
  const float* wts  = (const float*)d_in[2];
  const float* bias = (const float*)d_in[3];
  const int*   rows = (const int*)d_in[4];
  const int*   cols = (const int*)d_in[5];
  float* out = (float*)d_out;

  const size_t S = (size_t)B_ * N_ * C_ * sizeof(float);   // 33.5 MB
  char* ws = (char*)d_ws;
  float* cheb1 = (float*)ws;
  float* cheb2 = (float*)(ws + S);
  char* meta = ws + 2 * S;
  int* cnt  = (int*)meta;                        // B*N*4      = 262144 B
  int* cur  = (int*)(meta + 262144);             // B*N*4      = 262144 B
  int* off  = (int*)(meta + 524288);             // B*(N+1)*4  = 262208 B
  int2* ecv = (int2*)(meta + 1048576);           // B*E*8      = 8 MB
  unsigned short* wf = (unsigned short*)(meta + 1048576 + 8388608);  // 128 KB

  // zero cnt + cur (131072 ints)
  zero_kernel<<<512, 256, 0, stream>>>(cnt);
  wfrag_kernel<<<256, 256, 0, stream>>>(wts, wf);
  hist_kernel<<<(B_ * E_) / 256, 256, 0, stream>>>(rows, cnt);
  scan_kernel<<<B_, 256, 0, stream>>>(cnt, off);
  scatter_kernel<<<(B_ * E_) / 256, 256, 0, stream>>>(rows, cols, vals, off, cur, ecv);
  // cheb1 = L x
  spmm_kernel<<<(B_ * N_) / 4, 256, 0, stream>>>(x, nullptr, cheb1, ecv, off, 1.f, 0.f);
  // cheb2 = 2 L cheb1 - x
  spmm_kernel<<<(B_ * N_) / 4, 256, 0, stream>>>(cheb1, x, cheb2, ecv, off, 2.f, -1.f);
  // cheb3 = 2 L cheb2 - cheb1   (stored in d_out)
  spmm_kernel<<<(B_ * N_) / 4, 256, 0, stream>>>(cheb2, cheb1, out, ecv, off, 2.f, -1.f);
  // out = relu(bias + x@W0 + c1@W1 + c2@W2 + c3@W3)
  gemm_kernel<<<(B_ * N_) / 64, 256, 0, stream>>>(x, cheb1, cheb2, out, wf, bias, out);
}